// Round 2
// baseline (381.237 us; speedup 1.0000x reference)
//
#include <hip/hip_runtime.h>

// Problem: M=65536, K=512, N=512
//   x_scale = max(|x|)/127 (>= 1e-5); x_int8 = clip(rint(x/x_scale));
//   out = (x_int8 @ W^T).f32 * (x_scale * wscale[n])
//
// R7: single fused kernel with manual grid barrier (512 blocks = 2/CU,
// co-residency guaranteed by __launch_bounds__(256,2) + 64 KB LDS).
//   Phase A: each block loads the a0-half of its 128-row M-strip into
//     128 VGPRs (held across the barrier), absmax of the full strip,
//     blocks 0..63 repack the 1 MB int32 weight -> 256 KB int8.
//   Grid barrier (atomic counter in ws, zeroed by a memset node).
//   Phase B: reduce 512 partials (agent-scope loads) -> scale;
//     quantize the held half reg->reg into A fragments (no LDS, no re-read);
//     re-read only the a1-half (64 MB total, L3-hot) and quantize.
//   Phase C: 4 N-tiles; B staged via global_load_lds in fragment order;
//     next-tile staging issued BEFORE the epilogue stores so both drain
//     in parallel at the loop-top barrier. B(0) issued right after the
//     grid barrier to hide its latency under quant VALU.
// vs R6: -1 launch, -64 MB L3 read, -A-LDS round-trip (+swizzle VALU),
//        -1 stage stall; + barrier (~2 us) + 4-byte memset.

#define M_DIM 65536
#define K_DIM 512
#define N_DIM 512
#define EPSF  1e-5f
#define GRID  512

typedef int int32x4 __attribute__((ext_vector_type(4)));

// ---- ws layout (bytes) ----
#define WS_CNT    0                         // 4 B barrier counter
#define WS_PART   256                       // 512 float partials (2 KB)
#define WS_WPACK  32768                     // packed int8 weight (256 KB)

__device__ inline unsigned int pack_w4(int4 v) {
    return (v.x & 0xff) | ((v.y & 0xff) << 8) |
           ((v.z & 0xff) << 16) | ((unsigned)v.w << 24);
}

// quantize 4 floats -> 4 packed int8 (RNE magic constant; no clamp needed
// since |x*inv| <= ~127.00002).
__device__ inline unsigned int quantpack4(float4 f, float inv) {
    const float C = 12582912.0f;  // 1.5 * 2^23
    unsigned int u0 = __float_as_uint(fmaf(f.x, inv, C));
    unsigned int u1 = __float_as_uint(fmaf(f.y, inv, C));
    unsigned int u2 = __float_as_uint(fmaf(f.z, inv, C));
    unsigned int u3 = __float_as_uint(fmaf(f.w, inv, C));
    unsigned int lo = __builtin_amdgcn_perm(u1, u0, 0x0C0C0400u);
    unsigned int hi = __builtin_amdgcn_perm(u3, u2, 0x04000C0Cu);
    return lo | hi;
}

__global__ __launch_bounds__(256, 2) void fused_kernel(
    const float* __restrict__ x, const int* __restrict__ wi,
    const float* __restrict__ wscale, unsigned int* __restrict__ ws,
    float* __restrict__ out) {
    __shared__ __attribute__((aligned(16))) signed char Blds[64 * 1024];
    __shared__ float red[4];

    unsigned int* cnt      = ws + (WS_CNT >> 2);
    unsigned int* partials = ws + (WS_PART >> 2);   // floats as u32 bits
    unsigned int* wp       = ws + (WS_WPACK >> 2);
    const signed char* w8  = (const signed char*)wp;

    const int t    = threadIdx.x;
    const int wave = t >> 6;
    const int lane = t & 63;
    const int quad = lane >> 4;
    const int l16  = lane & 15;
    const int b    = blockIdx.x;
    const int m0   = b * 128;
    const int mw   = m0 + wave * 32;

    // per-thread A-fragment source rows
    const float* xr0 = x + (size_t)(mw + l16) * K_DIM + quad * 16;
    const float* xr1 = xr0 + (size_t)16 * K_DIM;

    // ---- Phase A: hold a0-half in 128 VGPRs; absmax of full strip ----
    float4 h[32];
    float m = 0.0f;
    #pragma unroll
    for (int k = 0; k < 8; ++k) {
        #pragma unroll
        for (int j = 0; j < 4; ++j) {
            float4 v = *(const float4*)(xr0 + k * 64 + j * 4);
            h[k * 4 + j] = v;
            m = fmaxf(m, fmaxf(fmaxf(fabsf(v.x), fabsf(v.y)),
                               fmaxf(fabsf(v.z), fabsf(v.w))));
        }
    }
    #pragma unroll
    for (int k = 0; k < 8; ++k) {
        #pragma unroll
        for (int j = 0; j < 4; ++j) {
            float4 v = *(const float4*)(xr1 + k * 64 + j * 4);
            m = fmaxf(m, fmaxf(fmaxf(fabsf(v.x), fabsf(v.y)),
                               fmaxf(fabsf(v.z), fabsf(v.w))));
        }
    }

    // weight repack (blocks 0..63): 1 MB int32 -> 256 KB int8
    if (b < 64) {
        #pragma unroll
        for (int j = 0; j < 4; ++j) {
            int d = b * 1024 + j * 256 + t;
            wp[d] = pack_w4(((const int4*)wi)[d]);
        }
    }

    // block absmax -> partials[b]
    #pragma unroll
    for (int off = 32; off > 0; off >>= 1)
        m = fmaxf(m, __shfl_xor(m, off));
    if (lane == 0) red[wave] = m;
    __syncthreads();
    if (t == 0)
        partials[b] = __float_as_uint(
            fmaxf(fmaxf(red[0], red[1]), fmaxf(red[2], red[3])));

    // ---- grid barrier (all 512 blocks co-resident) ----
    __threadfence();            // flush partials + wp device-wide
    __syncthreads();            // all threads fenced before arrive
    if (t == 0) {
        __hip_atomic_fetch_add(cnt, 1u, __ATOMIC_ACQ_REL,
                               __HIP_MEMORY_SCOPE_AGENT);
        while (__hip_atomic_load(cnt, __ATOMIC_ACQUIRE,
                                 __HIP_MEMORY_SCOPE_AGENT) != GRID)
            __builtin_amdgcn_s_sleep(8);
    }
    __syncthreads();

    // ---- issue B(0) staging early: latency hides under quant VALU ----
    #pragma unroll
    for (int cc = 0; cc < 2; ++cc) {
        int c = wave * 2 + cc;
        #pragma unroll
        for (int tt = 0; tt < 8; ++tt) {
            const signed char* g = w8 + (long)(tt * 16 + l16) * K_DIM
                                      + c * 64 + quad * 16;
            __builtin_amdgcn_global_load_lds(
                (const __attribute__((address_space(1))) unsigned int*)g,
                (__attribute__((address_space(3))) unsigned int*)(Blds + (c * 8 + tt) * 1024),
                16, 0, 0);
        }
    }

    // ---- reduce 512 partials (agent loads; stale-cache safe) ----
    {
        float v0 = __uint_as_float(__hip_atomic_load(
            &partials[t], __ATOMIC_RELAXED, __HIP_MEMORY_SCOPE_AGENT));
        float v1 = __uint_as_float(__hip_atomic_load(
            &partials[t + 256], __ATOMIC_RELAXED, __HIP_MEMORY_SCOPE_AGENT));
        float mm = fmaxf(v0, v1);
        #pragma unroll
        for (int off = 32; off > 0; off >>= 1)
            mm = fmaxf(mm, __shfl_xor(mm, off));
        if (lane == 0) red[wave] = mm;
    }
    __syncthreads();
    const float mx  = fmaxf(fmaxf(red[0], red[1]), fmaxf(red[2], red[3]));
    const float s   = fmaxf(mx / 127.0f, EPSF);
    const float inv = 1.0f / s;

    // ---- quantize: held half reg->reg; a1 half re-read from L3 ----
    int32x4 a0[8], a1[8];
    #pragma unroll
    for (int k = 0; k < 8; ++k) {
        a0[k].x = (int)quantpack4(h[k * 4 + 0], inv);
        a0[k].y = (int)quantpack4(h[k * 4 + 1], inv);
        a0[k].z = (int)quantpack4(h[k * 4 + 2], inv);
        a0[k].w = (int)quantpack4(h[k * 4 + 3], inv);
    }
    #pragma unroll
    for (int k = 0; k < 8; ++k) {
        float4 v0 = *(const float4*)(xr1 + k * 64 + 0);
        float4 v1 = *(const float4*)(xr1 + k * 64 + 4);
        float4 v2 = *(const float4*)(xr1 + k * 64 + 8);
        float4 v3 = *(const float4*)(xr1 + k * 64 + 12);
        a1[k].x = (int)quantpack4(v0, inv);
        a1[k].y = (int)quantpack4(v1, inv);
        a1[k].z = (int)quantpack4(v2, inv);
        a1[k].w = (int)quantpack4(v3, inv);
    }

    // ---- GEMM over 4 N-tiles ----
    for (int bx = 0; bx < 4; ++bx) {
        const int n0 = bx * 128;
        __syncthreads();                     // stage(bx) + prior stores drained

        int32x4 acc0[8] = {};
        int32x4 acc1[8] = {};
        #pragma unroll
        for (int k = 0; k < 8; ++k) {
            const signed char* bbase = Blds + k * 8192 + lane * 16;
            #pragma unroll
            for (int tt = 0; tt < 8; ++tt) {
                int32x4 bfrag = *(const int32x4*)(bbase + tt * 1024);
                acc0[tt] = __builtin_amdgcn_mfma_i32_16x16x64_i8(a0[k], bfrag, acc0[tt], 0, 0, 0);
                acc1[tt] = __builtin_amdgcn_mfma_i32_16x16x64_i8(a1[k], bfrag, acc1[tt], 0, 0, 0);
            }
        }
        __syncthreads();                     // all waves done reading Blds(bx)

        // stage next B tile BEFORE epilogue: overlaps with store drain
        if (bx < 3) {
            const int n1 = (bx + 1) * 128;
            #pragma unroll
            for (int cc = 0; cc < 2; ++cc) {
                int c = wave * 2 + cc;
                #pragma unroll
                for (int tt = 0; tt < 8; ++tt) {
                    const signed char* g = w8 + (long)(n1 + tt * 16 + l16) * K_DIM
                                              + c * 64 + quad * 16;
                    __builtin_amdgcn_global_load_lds(
                        (const __attribute__((address_space(1))) unsigned int*)g,
                        (__attribute__((address_space(3))) unsigned int*)(Blds + (c * 8 + tt) * 1024),
                        16, 0, 0);
                }
            }
        }

        // epilogue for this N-tile
        #pragma unroll
        for (int tt = 0; tt < 8; ++tt) {
            int n = n0 + tt * 16 + l16;
            float c = s * wscale[n];
            float* o0 = out + (long)(mw + quad * 4) * N_DIM + n;
            float* o1 = o0 + (long)16 * N_DIM;
            #pragma unroll
            for (int r = 0; r < 4; ++r) {
                o0[(long)r * N_DIM] = (float)acc0[tt][r] * c;
                o1[(long)r * N_DIM] = (float)acc1[tt][r] * c;
            }
        }
    }
}

extern "C" void kernel_launch(void* const* d_in, const int* in_sizes, int n_in,
                              void* d_out, int out_size, void* d_ws, size_t ws_size,
                              hipStream_t stream) {
    const float* x   = (const float*)d_in[0];
    const int*   wi  = (const int*)d_in[1];    // int8 values stored as int32
    const float* sc  = (const float*)d_in[2];
    float*       out = (float*)d_out;

    // zero the barrier counter (graph-capturable memset node)
    hipMemsetAsync(d_ws, 0, 4, stream);

    fused_kernel<<<GRID, 256, 0, stream>>>(x, wi, sc, (unsigned int*)d_ws, out);
}

// Round 3
// 279.914 us; speedup vs baseline: 1.3620x; 1.3620x over previous
//
#include <hip/hip_runtime.h>

// Problem: M=65536, K=512, N=512
//   x_scale = max(|x|)/127 (>= 1e-5); x_int8 = clip(rint(x/x_scale));
//   out = (x_int8 @ W^T).f32 * (x_scale * wscale[n])
//
// R8: two kernels (R7 single-kernel fusion regressed: streaming phases ran
// at GEMM occupancy, 215 us alone).
//   k1 (unchanged, proven): 4096-chunk absmax partials + weight repack.
//   k2 (reworked for occupancy): 1024 blocks x 256 thr, 64-row M-strips,
//     B-tile 64N x 512K = 32 KB LDS -> 4 blocks/CU (16 waves, ~46% occ,
//     vs R6's 2 blocks/CU at 23%). Wave owns 16 rows; A quantized
//     DIRECTLY global->reg in fragment order (no A-LDS round-trip).
//     B(0) staged at kernel entry; latency hides under partials-reduce
//     + quant. Per N-tile: sync -> MFMA -> sync -> stage(next) -> epilogue.

#define M_DIM 65536
#define K_DIM 512
#define N_DIM 512
#define EPSF  1e-5f

typedef int int32x4 __attribute__((ext_vector_type(4)));

// ---- ws layout (bytes) ----
#define WS_PART   256                       // 4096 float partials (16 KB)
#define WS_WPACK  32768                     // packed int8 weight (256 KB)

__device__ inline unsigned int pack_w4(int4 v) {
    return (v.x & 0xff) | ((v.y & 0xff) << 8) |
           ((v.z & 0xff) << 16) | ((unsigned)v.w << 24);
}

// quantize 4 floats -> 4 packed int8 (RNE magic constant; no clamp needed
// since |x*inv| <= ~127.00002).
__device__ inline unsigned int quantpack4(float4 f, float inv) {
    const float C = 12582912.0f;  // 1.5 * 2^23
    unsigned int u0 = __float_as_uint(fmaf(f.x, inv, C));
    unsigned int u1 = __float_as_uint(fmaf(f.y, inv, C));
    unsigned int u2 = __float_as_uint(fmaf(f.z, inv, C));
    unsigned int u3 = __float_as_uint(fmaf(f.w, inv, C));
    unsigned int lo = __builtin_amdgcn_perm(u1, u0, 0x0C0C0400u);
    unsigned int hi = __builtin_amdgcn_perm(u3, u2, 0x04000C0Cu);
    return lo | hi;
}

// ---------------- Kernel 1: absmax partials + weight repack (fused grid) ----
// blocks 0..4095: partial absmax of a contiguous 32 KB chunk of x.
// blocks 4096..4159: repack the 1 MB int32 weight into 256 KB int8.
__global__ void absmax1_pack_kernel(const float* __restrict__ x,
                                    const int* __restrict__ wi,
                                    float* __restrict__ partials,
                                    unsigned int* __restrict__ wp) {
    const int b = blockIdx.x;
    const int t = threadIdx.x;
    if (b < 4096) {
        __shared__ float red[4];
        const float4* x4 = (const float4*)x;
        const int base = b * 2048;               // float4 units (32 KB chunk)
        float m = 0.0f;
        #pragma unroll
        for (int j = 0; j < 8; ++j) {
            float4 v = x4[base + j * 256 + t];
            m = fmaxf(m, fmaxf(fmaxf(fabsf(v.x), fabsf(v.y)),
                               fmaxf(fabsf(v.z), fabsf(v.w))));
        }
        #pragma unroll
        for (int off = 32; off > 0; off >>= 1)
            m = fmaxf(m, __shfl_xor(m, off));
        if ((t & 63) == 0) red[t >> 6] = m;
        __syncthreads();
        if (t == 0)
            partials[b] = fmaxf(fmaxf(red[0], red[1]), fmaxf(red[2], red[3]));
    } else {
        const int bb = b - 4096;
        #pragma unroll
        for (int j = 0; j < 4; ++j) {
            int d = bb * 1024 + j * 256 + t;     // packed dword index
            wp[d] = pack_w4(((const int4*)wi)[d]);
        }
    }
}

// ---------------- Kernel 2: fused quant + int8 GEMM + dequant --------------
// 1024 blocks x 256 threads (4 waves), 4 blocks/CU (32 KB LDS). Block owns
// M-strip [64*blockIdx, +64); wave owns 16 rows. A fragments quantized
// straight from L3-hot x into registers. LDS holds one 64N x 512K B-tile
// in fragment order; 8 N-tiles per strip.
__global__ __launch_bounds__(256, 4) void quant_gemm_kernel(
    const float* __restrict__ x, const signed char* __restrict__ w,
    const float* __restrict__ wscale, const float* __restrict__ partials,
    float* __restrict__ out) {
    __shared__ __attribute__((aligned(16))) signed char Blds[32 * 1024];
    __shared__ float red[4];

    const int t    = threadIdx.x;
    const int wave = t >> 6;
    const int lane = t & 63;
    const int quad = lane >> 4;
    const int l16  = lane & 15;
    const int m0   = blockIdx.x * 64;
    const int mw   = m0 + wave * 16;

    // ---- issue B(0) staging first: latency hides under reduce + quant ----
    // layout: [c = k/64 (8)][tt = n/16 (4)][lane][16B]
    #pragma unroll
    for (int cc = 0; cc < 2; ++cc) {
        int c = wave * 2 + cc;
        #pragma unroll
        for (int tt = 0; tt < 4; ++tt) {
            const signed char* g = w + (long)(tt * 16 + l16) * K_DIM
                                     + c * 64 + quad * 16;
            __builtin_amdgcn_global_load_lds(
                (const __attribute__((address_space(1))) unsigned int*)g,
                (__attribute__((address_space(3))) unsigned int*)(Blds + (c * 4 + tt) * 1024),
                16, 0, 0);
        }
    }

    // ---- reduce 4096 partials -> scale (16 KB, L2 broadcast) ----
    float m = 0.0f;
    {
        const float4* p4 = (const float4*)partials;
        #pragma unroll
        for (int j = 0; j < 4; ++j) {
            float4 v = p4[t + j * 256];
            m = fmaxf(m, fmaxf(fmaxf(v.x, v.y), fmaxf(v.z, v.w)));
        }
        #pragma unroll
        for (int off = 32; off > 0; off >>= 1)
            m = fmaxf(m, __shfl_xor(m, off));
        if (lane == 0) red[wave] = m;
    }
    __syncthreads();
    const float mx  = fmaxf(fmaxf(red[0], red[1]), fmaxf(red[2], red[3]));
    const float s   = fmaxf(mx / 127.0f, EPSF);
    const float inv = 1.0f / s;

    // ---- quantize own 16 rows straight into A fragments (L3-hot x) ----
    // thread (l16, quad): row mw+l16, cols quad*16 + k*64 .. +16
    int32x4 a[8];
    {
        const float* xr = x + (size_t)(mw + l16) * K_DIM + quad * 16;
        #pragma unroll
        for (int k = 0; k < 8; ++k) {
            float4 v0 = *(const float4*)(xr + k * 64 + 0);
            float4 v1 = *(const float4*)(xr + k * 64 + 4);
            float4 v2 = *(const float4*)(xr + k * 64 + 8);
            float4 v3 = *(const float4*)(xr + k * 64 + 12);
            a[k].x = (int)quantpack4(v0, inv);
            a[k].y = (int)quantpack4(v1, inv);
            a[k].z = (int)quantpack4(v2, inv);
            a[k].w = (int)quantpack4(v3, inv);
        }
    }

    // ---- GEMM over 8 N-tiles of 64 cols ----
    for (int bx = 0; bx < 8; ++bx) {
        const int n0 = bx * 64;
        __syncthreads();                     // stage(bx) drained

        int32x4 acc[4] = {};
        #pragma unroll
        for (int k = 0; k < 8; ++k) {
            const signed char* bbase = Blds + k * 4096 + lane * 16;
            #pragma unroll
            for (int tt = 0; tt < 4; ++tt) {
                int32x4 bf = *(const int32x4*)(bbase + tt * 1024);
                acc[tt] = __builtin_amdgcn_mfma_i32_16x16x64_i8(a[k], bf, acc[tt], 0, 0, 0);
            }
        }
        __syncthreads();                     // all waves done reading Blds(bx)

        // stage next B tile BEFORE epilogue: overlaps with store traffic
        if (bx < 7) {
            const int n1 = (bx + 1) * 64;
            #pragma unroll
            for (int cc = 0; cc < 2; ++cc) {
                int c = wave * 2 + cc;
                #pragma unroll
                for (int tt = 0; tt < 4; ++tt) {
                    const signed char* g = w + (long)(n1 + tt * 16 + l16) * K_DIM
                                             + c * 64 + quad * 16;
                    __builtin_amdgcn_global_load_lds(
                        (const __attribute__((address_space(1))) unsigned int*)g,
                        (__attribute__((address_space(3))) unsigned int*)(Blds + (c * 4 + tt) * 1024),
                        16, 0, 0);
                }
            }
        }

        // epilogue for this N-tile
        #pragma unroll
        for (int tt = 0; tt < 4; ++tt) {
            int n = n0 + tt * 16 + l16;
            float c = s * wscale[n];
            float* o = out + (long)(mw + quad * 4) * N_DIM + n;
            #pragma unroll
            for (int r = 0; r < 4; ++r)
                o[(long)r * N_DIM] = (float)acc[tt][r] * c;
        }
    }
}

extern "C" void kernel_launch(void* const* d_in, const int* in_sizes, int n_in,
                              void* d_out, int out_size, void* d_ws, size_t ws_size,
                              hipStream_t stream) {
    const float* x   = (const float*)d_in[0];
    const int*   wi  = (const int*)d_in[1];    // int8 values stored as int32
    const float* sc  = (const float*)d_in[2];
    float*       out = (float*)d_out;

    float*        partials = (float*)((char*)d_ws + WS_PART);
    unsigned int* wp       = (unsigned int*)((char*)d_ws + WS_WPACK);
    const signed char* w8  = (const signed char*)wp;

    absmax1_pack_kernel<<<4160, 256, 0, stream>>>(x, wi, partials, wp);
    quant_gemm_kernel<<<1024, 256, 0, stream>>>(x, w8, sc, partials, out);
}

// Round 4
// 274.923 us; speedup vs baseline: 1.3867x; 1.0182x over previous
//
#include <hip/hip_runtime.h>

// Problem: M=65536, K=512, N=512
//   x_scale = max(|x|)/127 (>= 1e-5); x_int8 = clip(rint(x/x_scale));
//   out = (x_int8 @ W^T).f32 * (x_scale * wscale[n])
//
// R9 = R6's coalesced quant->LDS A-path  x  R8's 4-blocks/CU occupancy.
//   k1 (unchanged, proven): 4096-chunk absmax partials + weight repack.
//   k2: 1024 blocks x 256 thr, 64-row M-strips, ONE 32 KB LDS buffer
//     time-shared (A strip 64x512 int8 = 32 KB, then B tile 64Nx512K):
//       reduce partials -> scale
//       coalesced quant of 128 KB fp32 strip -> XOR-swizzled LDS
//       wave pulls its 8 A-fragments to regs (32 VGPR); LDS freed
//       8 N-tiles: sync -> MFMA -> sync -> stage(next) -> epilogue
//     -> 4 blocks/CU (vs R6's 2), launch_bounds(256,4).
//   R8's regression was the direct global->reg A gather (16 B used per
//   64 B line at 2 KB row stride = 4x transaction inflation on 128 MB);
//   this restores R6's perfectly-coalesced x read.

#define M_DIM 65536
#define K_DIM 512
#define N_DIM 512
#define EPSF  1e-5f

typedef int int32x4 __attribute__((ext_vector_type(4)));

// ---- ws layout (bytes) ----
#define WS_PART   256                       // 4096 float partials (16 KB)
#define WS_WPACK  32768                     // packed int8 weight (256 KB)

__device__ inline unsigned int pack_w4(int4 v) {
    return (v.x & 0xff) | ((v.y & 0xff) << 8) |
           ((v.z & 0xff) << 16) | ((unsigned)v.w << 24);
}

// quantize 4 floats -> 4 packed int8 (RNE magic constant; no clamp needed
// since |x*inv| <= ~127.00002).
__device__ inline unsigned int quantpack4(float4 f, float inv) {
    const float C = 12582912.0f;  // 1.5 * 2^23
    unsigned int u0 = __float_as_uint(fmaf(f.x, inv, C));
    unsigned int u1 = __float_as_uint(fmaf(f.y, inv, C));
    unsigned int u2 = __float_as_uint(fmaf(f.z, inv, C));
    unsigned int u3 = __float_as_uint(fmaf(f.w, inv, C));
    unsigned int lo = __builtin_amdgcn_perm(u1, u0, 0x0C0C0400u);
    unsigned int hi = __builtin_amdgcn_perm(u3, u2, 0x04000C0Cu);
    return lo | hi;
}

// ---------------- Kernel 1: absmax partials + weight repack (fused grid) ----
// blocks 0..4095: partial absmax of a contiguous 32 KB chunk of x.
// blocks 4096..4159: repack the 1 MB int32 weight into 256 KB int8.
__global__ void absmax1_pack_kernel(const float* __restrict__ x,
                                    const int* __restrict__ wi,
                                    float* __restrict__ partials,
                                    unsigned int* __restrict__ wp) {
    const int b = blockIdx.x;
    const int t = threadIdx.x;
    if (b < 4096) {
        __shared__ float red[4];
        const float4* x4 = (const float4*)x;
        const int base = b * 2048;               // float4 units (32 KB chunk)
        float m = 0.0f;
        #pragma unroll
        for (int j = 0; j < 8; ++j) {
            float4 v = x4[base + j * 256 + t];
            m = fmaxf(m, fmaxf(fmaxf(fabsf(v.x), fabsf(v.y)),
                               fmaxf(fabsf(v.z), fabsf(v.w))));
        }
        #pragma unroll
        for (int off = 32; off > 0; off >>= 1)
            m = fmaxf(m, __shfl_xor(m, off));
        if ((t & 63) == 0) red[t >> 6] = m;
        __syncthreads();
        if (t == 0)
            partials[b] = fmaxf(fmaxf(red[0], red[1]), fmaxf(red[2], red[3]));
    } else {
        const int bb = b - 4096;
        #pragma unroll
        for (int j = 0; j < 4; ++j) {
            int d = bb * 1024 + j * 256 + t;     // packed dword index
            wp[d] = pack_w4(((const int4*)wi)[d]);
        }
    }
}

// ---------------- Kernel 2: fused quant + int8 GEMM + dequant --------------
// 1024 blocks x 256 threads (4 waves), 4 blocks/CU (32 KB LDS time-shared).
__global__ __launch_bounds__(256, 4) void quant_gemm_kernel(
    const float* __restrict__ x, const signed char* __restrict__ w,
    const float* __restrict__ wscale, const float* __restrict__ partials,
    float* __restrict__ out) {
    __shared__ __attribute__((aligned(16))) signed char Lds[32 * 1024];
    __shared__ float red[4];

    const int t    = threadIdx.x;
    const int wave = t >> 6;
    const int lane = t & 63;
    const int quad = lane >> 4;
    const int l16  = lane & 15;
    const int m0   = blockIdx.x * 64;
    const int mw   = m0 + wave * 16;

    // ---- reduce 4096 partials -> scale (16 KB, L2 broadcast) ----
    float m = 0.0f;
    {
        const float4* p4 = (const float4*)partials;
        #pragma unroll
        for (int j = 0; j < 4; ++j) {
            float4 v = p4[t + j * 256];
            m = fmaxf(m, fmaxf(fmaxf(v.x, v.y), fmaxf(v.z, v.w)));
        }
        #pragma unroll
        for (int off = 32; off > 0; off >>= 1)
            m = fmaxf(m, __shfl_xor(m, off));
        if (lane == 0) red[wave] = m;
    }
    __syncthreads();
    const float mx  = fmaxf(fmaxf(red[0], red[1]), fmaxf(red[2], red[3]));
    const float s   = fmaxf(mx / 127.0f, EPSF);
    const float inv = 1.0f / s;

    // ---- quantize own strip (128 KB fp32, L3-hot) into swizzled A-LDS ----
    // thread t, iter j: 4 consecutive float4 = 16 floats = one 16 B LDS slot
    // at (row = j*8 + t/32, bytecol = (t&31)*16), byte ^= (row&7)<<4.
    {
        const float4* xs = (const float4*)(x + (size_t)m0 * K_DIM);
        const int rsub = t >> 5;
        const int csub = (t & 31) * 16;
        #pragma unroll
        for (int j = 0; j < 8; ++j) {
            const int fi = j * 1024 + t * 4;     // float4 index in strip
            float4 v0 = xs[fi + 0];
            float4 v1 = xs[fi + 1];
            float4 v2 = xs[fi + 2];
            float4 v3 = xs[fi + 3];
            int32x4 p;
            p.x = (int)quantpack4(v0, inv);
            p.y = (int)quantpack4(v1, inv);
            p.z = (int)quantpack4(v2, inv);
            p.w = (int)quantpack4(v3, inv);
            const int row  = j * 8 + rsub;
            const int addr = (row * 512 + csub) ^ ((row & 7) << 4);
            *(int32x4*)(Lds + addr) = p;
        }
    }
    __syncthreads();

    // ---- A fragments -> registers (32 VGPR); then LDS is free for B ----
    int32x4 a[8];
    {
        const int r = wave * 16 + l16;
        #pragma unroll
        for (int k = 0; k < 8; ++k) {
            const int c = quad * 16 + k * 64;
            a[k] = *(const int32x4*)(Lds + ((r * 512 + c) ^ ((r & 7) << 4)));
        }
    }
    __syncthreads();   // every wave done reading A before B staging

    // ---- stage B(0) in fragment order [c=k/64 (8)][tt=n/16 (4)][lane][16B]
    #pragma unroll
    for (int cc = 0; cc < 2; ++cc) {
        int c = wave * 2 + cc;
        #pragma unroll
        for (int tt = 0; tt < 4; ++tt) {
            const signed char* g = w + (long)(tt * 16 + l16) * K_DIM
                                     + c * 64 + quad * 16;
            __builtin_amdgcn_global_load_lds(
                (const __attribute__((address_space(1))) unsigned int*)g,
                (__attribute__((address_space(3))) unsigned int*)(Lds + (c * 4 + tt) * 1024),
                16, 0, 0);
        }
    }

    // ---- GEMM over 8 N-tiles of 64 cols ----
    for (int bx = 0; bx < 8; ++bx) {
        const int n0 = bx * 64;
        __syncthreads();                     // stage(bx) drained

        int32x4 acc[4] = {};
        #pragma unroll
        for (int k = 0; k < 8; ++k) {
            const signed char* bbase = Lds + k * 4096 + lane * 16;
            #pragma unroll
            for (int tt = 0; tt < 4; ++tt) {
                int32x4 bf = *(const int32x4*)(bbase + tt * 1024);
                acc[tt] = __builtin_amdgcn_mfma_i32_16x16x64_i8(a[k], bf, acc[tt], 0, 0, 0);
            }
        }
        __syncthreads();                     // all waves done reading Lds(bx)

        // stage next B tile BEFORE epilogue: overlaps with store traffic
        if (bx < 7) {
            const int n1 = (bx + 1) * 64;
            #pragma unroll
            for (int cc = 0; cc < 2; ++cc) {
                int c = wave * 2 + cc;
                #pragma unroll
                for (int tt = 0; tt < 4; ++tt) {
                    const signed char* g = w + (long)(n1 + tt * 16 + l16) * K_DIM
                                             + c * 64 + quad * 16;
                    __builtin_amdgcn_global_load_lds(
                        (const __attribute__((address_space(1))) unsigned int*)g,
                        (__attribute__((address_space(3))) unsigned int*)(Lds + (c * 4 + tt) * 1024),
                        16, 0, 0);
                }
            }
        }

        // epilogue for this N-tile
        #pragma unroll
        for (int tt = 0; tt < 4; ++tt) {
            int n = n0 + tt * 16 + l16;
            float c = s * wscale[n];
            float* o = out + (long)(mw + quad * 4) * N_DIM + n;
            #pragma unroll
            for (int r = 0; r < 4; ++r)
                o[(long)r * N_DIM] = (float)acc[tt][r] * c;
        }
    }
}

extern "C" void kernel_launch(void* const* d_in, const int* in_sizes, int n_in,
                              void* d_out, int out_size, void* d_ws, size_t ws_size,
                              hipStream_t stream) {
    const float* x   = (const float*)d_in[0];
    const int*   wi  = (const int*)d_in[1];    // int8 values stored as int32
    const float* sc  = (const float*)d_in[2];
    float*       out = (float*)d_out;

    float*        partials = (float*)((char*)d_ws + WS_PART);
    unsigned int* wp       = (unsigned int*)((char*)d_ws + WS_WPACK);
    const signed char* w8  = (const signed char*)wp;

    absmax1_pack_kernel<<<4160, 256, 0, stream>>>(x, wi, partials, wp);
    quant_gemm_kernel<<<1024, 256, 0, stream>>>(x, w8, sc, partials, out);
}

// Round 5
// 273.504 us; speedup vs baseline: 1.3939x; 1.0052x over previous
//
#include <hip/hip_runtime.h>

// Problem: M=65536, K=512, N=512
//   x_scale = max(|x|)/127 (>= 1e-5); x_int8 = clip(rint(x/x_scale));
//   out = (x_int8 @ W^T).f32 * (x_scale * wscale[n])
//
// R10 = R6 (best measured: 265.7) + two surgical changes:
//  (a) k1 absmax via device atomicMax (positive float bits order as uint);
//      k2 reads the scalar at entry -> deletes k2's per-block reduce phase.
//  (b) anti-phase N-tile stagger: co-resident block pairs rotate their
//      4-tile loop 2 apart, so one block's epilogue store-drain (the
//      ~5 us/tile HBM write inside the barrier's vmcnt(0)) overlaps the
//      other block's MFMA phase. start = ((b ^ (b>>8)) & 1) * 2 covers
//      both (b,b+256) and (b,b+1) CU-pairing hypotheses.
// Everything else (quant->swizzled-LDS A path, fragment-order B staging,
// stage-next-before-epilogue, epilogue layout) is R6 verbatim.

#define M_DIM 65536
#define K_DIM 512
#define N_DIM 512
#define EPSF  1e-5f

typedef int int32x4 __attribute__((ext_vector_type(4)));

// ---- ws layout (bytes) ----
#define WS_ABS    0                         // 4 B absmax bits (memset to 0)
#define WS_WPACK  32768                     // packed int8 weight (256 KB)

__device__ inline unsigned int pack_w4(int4 v) {
    return (v.x & 0xff) | ((v.y & 0xff) << 8) |
           ((v.z & 0xff) << 16) | ((unsigned)v.w << 24);
}

// quantize 4 floats -> 4 packed int8 (RNE magic constant; no clamp needed
// since |x*inv| <= ~127.00002).
__device__ inline unsigned int quantpack4(float4 f, float inv) {
    const float C = 12582912.0f;  // 1.5 * 2^23
    unsigned int u0 = __float_as_uint(fmaf(f.x, inv, C));
    unsigned int u1 = __float_as_uint(fmaf(f.y, inv, C));
    unsigned int u2 = __float_as_uint(fmaf(f.z, inv, C));
    unsigned int u3 = __float_as_uint(fmaf(f.w, inv, C));
    unsigned int lo = __builtin_amdgcn_perm(u1, u0, 0x0C0C0400u);
    unsigned int hi = __builtin_amdgcn_perm(u3, u2, 0x04000C0Cu);
    return lo | hi;
}

// ---------------- Kernel 1: absmax (atomic) + weight repack (fused grid) ----
// blocks 0..4095: partial absmax of a contiguous 32 KB chunk of x ->
//   one device atomicMax on ws[0] (uint-ordered positive floats).
// blocks 4096..4159: repack the 1 MB int32 weight into 256 KB int8.
__global__ void absmax1_pack_kernel(const float* __restrict__ x,
                                    const int* __restrict__ wi,
                                    unsigned int* __restrict__ ws_abs,
                                    unsigned int* __restrict__ wp) {
    const int b = blockIdx.x;
    const int t = threadIdx.x;
    if (b < 4096) {
        __shared__ float red[4];
        const float4* x4 = (const float4*)x;
        const int base = b * 2048;               // float4 units (32 KB chunk)
        float m = 0.0f;
        #pragma unroll
        for (int j = 0; j < 8; ++j) {
            float4 v = x4[base + j * 256 + t];
            m = fmaxf(m, fmaxf(fmaxf(fabsf(v.x), fabsf(v.y)),
                               fmaxf(fabsf(v.z), fabsf(v.w))));
        }
        #pragma unroll
        for (int off = 32; off > 0; off >>= 1)
            m = fmaxf(m, __shfl_xor(m, off));
        if ((t & 63) == 0) red[t >> 6] = m;
        __syncthreads();
        if (t == 0) {
            float bm = fmaxf(fmaxf(red[0], red[1]), fmaxf(red[2], red[3]));
            atomicMax(ws_abs, __float_as_uint(bm));   // device scope
        }
    } else {
        const int bb = b - 4096;
        #pragma unroll
        for (int j = 0; j < 4; ++j) {
            int d = bb * 1024 + j * 256 + t;     // packed dword index
            wp[d] = pack_w4(((const int4*)wi)[d]);
        }
    }
}

// ---------------- Kernel 2: fused quant + int8 GEMM + dequant --------------
// 512 blocks x 256 threads (4 waves), 2 blocks/CU. Block owns M-strip
// [128*blockIdx, +128). One 64 KB LDS buffer, time-shared: A (swizzled int8
// strip) -> A frags to regs -> B tile staging per N-tile (staggered order).
__global__ __launch_bounds__(256, 2) void quant_gemm_kernel(
    const float* __restrict__ x, const signed char* __restrict__ w,
    const float* __restrict__ wscale, const unsigned int* __restrict__ ws_abs,
    float* __restrict__ out) {
    __shared__ __attribute__((aligned(16))) signed char Lds[64 * 1024];

    const int t    = threadIdx.x;
    const int wave = t >> 6;
    const int lane = t & 63;
    const int quad = lane >> 4;
    const int l16  = lane & 15;
    const int b    = blockIdx.x;
    const int m0   = b * 128;

    // ---- scale from k1's atomic absmax (no reduce phase) ----
    const float mx  = __uint_as_float(ws_abs[0]);
    const float s   = fmaxf(mx / 127.0f, EPSF);
    const float inv = 1.0f / s;

    // ---- quantize own strip (256 KB fp32, L3-hot) into swizzled A-LDS ----
    // thread t, iter j: 4 consecutive float4 = 16 floats = one 16 B LDS slot
    // at (row = j*8 + t/32, bytecol = (t&31)*16), byte ^= (row&7)<<4.
    {
        const float4* xs = (const float4*)(x + (size_t)m0 * K_DIM);
        const int rsub = t >> 5;
        const int csub = (t & 31) * 16;
        #pragma unroll
        for (int j = 0; j < 16; ++j) {
            const int fi = j * 1024 + t * 4;     // float4 index in strip
            float4 v0 = xs[fi + 0];
            float4 v1 = xs[fi + 1];
            float4 v2 = xs[fi + 2];
            float4 v3 = xs[fi + 3];
            int32x4 p;
            p.x = (int)quantpack4(v0, inv);
            p.y = (int)quantpack4(v1, inv);
            p.z = (int)quantpack4(v2, inv);
            p.w = (int)quantpack4(v3, inv);
            const int row  = j * 8 + rsub;
            const int addr = (row * 512 + csub) ^ ((row & 7) << 4);
            *(int32x4*)(Lds + addr) = p;
        }
    }
    __syncthreads();

    // ---- A fragments -> registers (64 VGPRs), then LDS is free for B ----
    int32x4 a0[8], a1[8];
    {
        const int r0 = wave * 32 + l16;
        const int r1 = r0 + 16;
        #pragma unroll
        for (int k = 0; k < 8; ++k) {
            const int c = quad * 16 + k * 64;
            a0[k] = *(const int32x4*)(Lds + ((r0 * 512 + c) ^ ((r0 & 7) << 4)));
            a1[k] = *(const int32x4*)(Lds + ((r1 * 512 + c) ^ ((r1 & 7) << 4)));
        }
    }
    __syncthreads();   // every wave done reading A before B staging

    const int mw = m0 + wave * 32;

    // anti-phase stagger: co-resident pair starts 2 tiles apart
    const int start = ((b ^ (b >> 8)) & 1) * 2;

    // stage first B tile (fragment order [c=k/64][tt][lane][16B])
    {
        const int n0 = ((start) & 3) * 128;
        #pragma unroll
        for (int cc = 0; cc < 2; ++cc) {
            int c = wave * 2 + cc;
            #pragma unroll
            for (int tt = 0; tt < 8; ++tt) {
                const signed char* g = w + (long)(n0 + tt * 16 + l16) * K_DIM
                                         + c * 64 + quad * 16;
                __builtin_amdgcn_global_load_lds(
                    (const __attribute__((address_space(1))) unsigned int*)g,
                    (__attribute__((address_space(3))) unsigned int*)(Lds + (c * 8 + tt) * 1024),
                    16, 0, 0);
            }
        }
    }

    for (int i = 0; i < 4; ++i) {
        const int bx = (start + i) & 3;
        const int n0 = bx * 128;
        __syncthreads();                     // stage(bx) drained

        int32x4 acc0[8] = {};
        int32x4 acc1[8] = {};
        #pragma unroll
        for (int k = 0; k < 8; ++k) {
            const signed char* bbase = Lds + k * 8192 + lane * 16;
            #pragma unroll
            for (int tt = 0; tt < 8; ++tt) {
                int32x4 bfrag = *(const int32x4*)(bbase + tt * 1024);
                acc0[tt] = __builtin_amdgcn_mfma_i32_16x16x64_i8(a0[k], bfrag, acc0[tt], 0, 0, 0);
                acc1[tt] = __builtin_amdgcn_mfma_i32_16x16x64_i8(a1[k], bfrag, acc1[tt], 0, 0, 0);
            }
        }
        __syncthreads();                     // all waves done reading Lds(bx)

        // stage next B tile BEFORE epilogue: overlaps with store traffic
        if (i < 3) {
            const int n1 = ((start + i + 1) & 3) * 128;
            #pragma unroll
            for (int cc = 0; cc < 2; ++cc) {
                int c = wave * 2 + cc;
                #pragma unroll
                for (int tt = 0; tt < 8; ++tt) {
                    const signed char* g = w + (long)(n1 + tt * 16 + l16) * K_DIM
                                             + c * 64 + quad * 16;
                    __builtin_amdgcn_global_load_lds(
                        (const __attribute__((address_space(1))) unsigned int*)g,
                        (__attribute__((address_space(3))) unsigned int*)(Lds + (c * 8 + tt) * 1024),
                        16, 0, 0);
                }
            }
        }

        // epilogue for this N-tile
        #pragma unroll
        for (int tt = 0; tt < 8; ++tt) {
            int n = n0 + tt * 16 + l16;
            float c = s * wscale[n];
            float* o0 = out + (long)(mw + quad * 4) * N_DIM + n;
            float* o1 = o0 + (long)16 * N_DIM;
            #pragma unroll
            for (int r = 0; r < 4; ++r) {
                o0[(long)r * N_DIM] = (float)acc0[tt][r] * c;
                o1[(long)r * N_DIM] = (float)acc1[tt][r] * c;
            }
        }
    }
}

extern "C" void kernel_launch(void* const* d_in, const int* in_sizes, int n_in,
                              void* d_out, int out_size, void* d_ws, size_t ws_size,
                              hipStream_t stream) {
    const float* x   = (const float*)d_in[0];
    const int*   wi  = (const int*)d_in[1];    // int8 values stored as int32
    const float* sc  = (const float*)d_in[2];
    float*       out = (float*)d_out;

    unsigned int* ws_abs = (unsigned int*)d_ws;
    unsigned int* wp     = (unsigned int*)((char*)d_ws + WS_WPACK);
    const signed char* w8 = (const signed char*)wp;

    // zero the absmax cell (graph-capturable memset node)
    hipMemsetAsync(d_ws, 0, 4, stream);

    absmax1_pack_kernel<<<4160, 256, 0, stream>>>(x, wi, ws_abs, wp);
    quant_gemm_kernel<<<512, 256, 0, stream>>>(x, w8, sc, ws_abs, out);
}